// Round 1
// baseline (218.726 us; speedup 1.0000x reference)
//
#include <hip/hip_runtime.h>

// Problem constants (SubOut_60206851555968): B=8, U=E=1024, D=P=256, fp32.
#define BDIM 8
#define UDIM 1024
#define EDIM 1024
#define DDIM 256
#define PDIM 256

// ---------------------------------------------------------------------------
// Kernel 1: shared Dense projection.
//   u_p[b,u,p] = u_enc[b,u,:] @ w[:,p] + bias[p]   (and same for e)
// Treated as one GEMM with 16384 rows (u rows then e rows), K=D=256, N=P=256.
// 64x64 tile per 256-thread block, 4x4 micro-tile per thread, BK=16.
// ---------------------------------------------------------------------------
__global__ __launch_bounds__(256) void proj_kernel(
    const float* __restrict__ u_enc, const float* __restrict__ e_enc,
    const float* __restrict__ w, const float* __restrict__ bias,
    float* __restrict__ u_p, float* __restrict__ e_p)
{
    __shared__ float As[16][68];   // [k][row], pad 68 keeps float4 alignment + no bad banks
    __shared__ float Bs[16][68];   // [k][col]

    int row0 = blockIdx.x * 64;
    int col0 = blockIdx.y * 64;
    const float* A;
    float* C;
    if (row0 < BDIM * UDIM) { A = u_enc; C = u_p; }
    else                    { A = e_enc; C = e_p; row0 -= BDIM * UDIM; }

    int tid = threadIdx.x;
    int tx = tid & 15, ty = tid >> 4;

    float acc[4][4] = {};

    for (int k0 = 0; k0 < DDIM; k0 += 16) {
        #pragma unroll
        for (int e = 0; e < 4; ++e) {
            int idx = tid + e * 256;
            int r  = idx >> 4, kk = idx & 15;       // A tile: 64 rows x 16 k
            As[kk][r] = A[(size_t)(row0 + r) * DDIM + (k0 + kk)];
            int kb = idx >> 6, cb = idx & 63;       // W tile: 16 k x 64 cols
            Bs[kb][cb] = w[(size_t)(k0 + kb) * PDIM + (col0 + cb)];
        }
        __syncthreads();
        #pragma unroll
        for (int kk = 0; kk < 16; ++kk) {
            float4 a4 = *(const float4*)&As[kk][ty * 4];
            float4 b4 = *(const float4*)&Bs[kk][tx * 4];
            float a[4]  = {a4.x, a4.y, a4.z, a4.w};
            float bv[4] = {b4.x, b4.y, b4.z, b4.w};
            #pragma unroll
            for (int i = 0; i < 4; ++i)
                #pragma unroll
                for (int j = 0; j < 4; ++j)
                    acc[i][j] += a[i] * bv[j];
        }
        __syncthreads();
    }

    #pragma unroll
    for (int i = 0; i < 4; ++i) {
        int r = row0 + ty * 4 + i;
        #pragma unroll
        for (int j = 0; j < 4; ++j) {
            int c = col0 + tx * 4 + j;
            C[(size_t)r * PDIM + c] = acc[i][j] + bias[c];
        }
    }
}

// ---------------------------------------------------------------------------
// Kernel 2: fused op-GEMM + sigmoid gate + row/col reduction.
//   op[b,u,e]   = ue_mask * (u_p[b,u,:] . e_p[b,e,:])
//   mask[b,u,e] = ue_mask * sigmoid(bpp_w*pair + bpp_b + op)
//   row_sums[b,u] += sum_e mask ; col_sums[b,e] += sum_u mask
// One 64x64 (u,e) tile per block; mask never touches HBM.
// ---------------------------------------------------------------------------
__global__ __launch_bounds__(256) void fused_kernel(
    const float* __restrict__ u_p, const float* __restrict__ e_p,
    const float* __restrict__ pair_enc, const float* __restrict__ ue_mask,
    const float* __restrict__ bpp_w_p, const float* __restrict__ bpp_b_p,
    float* __restrict__ row_sums, float* __restrict__ col_sums)
{
    __shared__ float As[16][68];
    __shared__ float Bs[16][68];
    __shared__ float rowred[64];
    __shared__ float colred[4][64];

    int b  = blockIdx.y;
    int iu = blockIdx.x >> 4, ie = blockIdx.x & 15;
    int u0 = iu * 64, e0 = ie * 64;

    int tid = threadIdx.x;
    int tx = tid & 15, ty = tid >> 4;

    const float* A  = u_p + (size_t)b * UDIM * PDIM;
    const float* Bm = e_p + (size_t)b * EDIM * PDIM;

    float acc[4][4] = {};

    for (int k0 = 0; k0 < PDIM; k0 += 16) {
        #pragma unroll
        for (int e = 0; e < 4; ++e) {
            int idx = tid + e * 256;
            int r = idx >> 4, kk = idx & 15;
            As[kk][r] = A [(size_t)(u0 + r) * PDIM + (k0 + kk)];
            Bs[kk][r] = Bm[(size_t)(e0 + r) * PDIM + (k0 + kk)];
        }
        __syncthreads();
        #pragma unroll
        for (int kk = 0; kk < 16; ++kk) {
            float4 a4 = *(const float4*)&As[kk][ty * 4];
            float4 b4 = *(const float4*)&Bs[kk][tx * 4];
            float a[4]  = {a4.x, a4.y, a4.z, a4.w};
            float bv[4] = {b4.x, b4.y, b4.z, b4.w};
            #pragma unroll
            for (int i = 0; i < 4; ++i)
                #pragma unroll
                for (int j = 0; j < 4; ++j)
                    acc[i][j] += a[i] * bv[j];
        }
        __syncthreads();
    }

    // Epilogue: gate + per-thread partial sums.
    float bw = bpp_w_p[0], bb = bpp_b_p[0];
    const float* pm = pair_enc + (size_t)b * UDIM * EDIM;
    const float* mm = ue_mask  + (size_t)b * UDIM * EDIM;

    float rsum[4] = {0.f, 0.f, 0.f, 0.f};
    float csum[4] = {0.f, 0.f, 0.f, 0.f};
    #pragma unroll
    for (int i = 0; i < 4; ++i) {
        int r = u0 + ty * 4 + i;
        float4 m4 = *(const float4*)&mm[(size_t)r * EDIM + e0 + tx * 4];
        float4 p4 = *(const float4*)&pm[(size_t)r * EDIM + e0 + tx * 4];
        float mv[4] = {m4.x, m4.y, m4.z, m4.w};
        float pv[4] = {p4.x, p4.y, p4.z, p4.w};
        #pragma unroll
        for (int j = 0; j < 4; ++j) {
            float arg = bw * pv[j] + bb + mv[j] * acc[i][j];
            float s = mv[j] / (1.0f + __expf(-arg));
            rsum[i] += s;
            csum[j] += s;
        }
    }

    // Row sums: reduce across tx (16 contiguous lanes). Leader writes LDS.
    #pragma unroll
    for (int i = 0; i < 4; ++i) {
        float v = rsum[i];
        v += __shfl_down(v, 8, 16);
        v += __shfl_down(v, 4, 16);
        v += __shfl_down(v, 2, 16);
        v += __shfl_down(v, 1, 16);
        if (tx == 0) rowred[ty * 4 + i] = v;   // unique writer per entry
    }

    // Col sums: reduce across the 4 ty values within each wave (stride-16 lanes).
    int wave = tid >> 6;
    int lane = tid & 63;
    #pragma unroll
    for (int j = 0; j < 4; ++j) {
        float v = csum[j];
        v += __shfl_down(v, 32, 64);
        v += __shfl_down(v, 16, 64);
        if (lane < 16) colred[wave][lane * 4 + j] = v;  // unique writer per entry
    }
    __syncthreads();

    if (tid < 64) {
        float v = colred[0][tid] + colred[1][tid] + colred[2][tid] + colred[3][tid];
        atomicAdd(&col_sums[(size_t)b * EDIM + e0 + tid], v);
    } else if (tid < 128) {
        int r = tid - 64;
        atomicAdd(&row_sums[(size_t)b * UDIM + u0 + r], rowred[r]);
    }
}

// ---------------------------------------------------------------------------
// Kernel 3: out[b, 0:256]   = sum_u row_sums[b,u] * u_enc[b,u,:]
//           out[b, 256:512] = sum_e col_sums[b,e] * e_enc[b,e,:]
// grid (B, 2, 16): each block does a 64-row chunk; atomicAdd into zeroed out.
// ---------------------------------------------------------------------------
__global__ __launch_bounds__(256) void finish_kernel(
    const float* __restrict__ u_enc, const float* __restrict__ e_enc,
    const float* __restrict__ row_sums, const float* __restrict__ col_sums,
    float* __restrict__ out)
{
    int b = blockIdx.x;
    int half = blockIdx.y;
    int chunk = blockIdx.z;          // 16 chunks of 64 rows
    int d = threadIdx.x;             // 256

    const float* enc = half ? e_enc : u_enc;
    const float* s   = half ? col_sums : row_sums;

    int base = chunk * 64;
    float acc = 0.f;
    #pragma unroll 4
    for (int u = 0; u < 64; ++u) {
        float sv = s[(size_t)b * UDIM + base + u];
        acc += sv * enc[(size_t)(b * UDIM + base + u) * DDIM + d];
    }
    atomicAdd(&out[(size_t)b * 2 * DDIM + half * DDIM + d], acc);
}

// ---------------------------------------------------------------------------
extern "C" void kernel_launch(void* const* d_in, const int* in_sizes, int n_in,
                              void* d_out, int out_size, void* d_ws, size_t ws_size,
                              hipStream_t stream)
{
    const float* u_enc    = (const float*)d_in[0];
    const float* e_enc    = (const float*)d_in[1];
    const float* pair_enc = (const float*)d_in[2];
    const float* ue_mask  = (const float*)d_in[3];
    const float* w_kernel = (const float*)d_in[4];
    const float* w_bias   = (const float*)d_in[5];
    const float* bpp_w    = (const float*)d_in[6];
    const float* bpp_b    = (const float*)d_in[7];
    float* out = (float*)d_out;

    // Workspace layout: u_p (8 MB) | e_p (8 MB) | row_sums (32 KB) | col_sums (32 KB)
    float* u_p      = (float*)d_ws;
    float* e_p      = u_p + (size_t)BDIM * UDIM * PDIM;
    float* row_sums = e_p + (size_t)BDIM * EDIM * PDIM;
    float* col_sums = row_sums + (size_t)BDIM * UDIM;

    hipMemsetAsync(row_sums, 0, (size_t)(BDIM * UDIM + BDIM * EDIM) * sizeof(float), stream);
    hipMemsetAsync(d_out, 0, (size_t)out_size * sizeof(float), stream);

    // 16384 rows / 64 = 256 row tiles; 256 cols / 64 = 4 col tiles.
    proj_kernel<<<dim3(256, 4), 256, 0, stream>>>(u_enc, e_enc, w_kernel, w_bias, u_p, e_p);

    // 16x16 (u,e) tiles x 8 batches.
    fused_kernel<<<dim3(256, BDIM), 256, 0, stream>>>(u_p, e_p, pair_enc, ue_mask,
                                                      bpp_w, bpp_b, row_sums, col_sums);

    finish_kernel<<<dim3(BDIM, 2, 16), 256, 0, stream>>>(u_enc, e_enc, row_sums, col_sums, out);
}

// Round 2
// 180.168 us; speedup vs baseline: 1.2140x; 1.2140x over previous
//
#include <hip/hip_runtime.h>

// Problem constants (SubOut_60206851555968): B=8, U=E=1024, D=P=256, fp32 in/out.
#define BDIM 8
#define UDIM 1024
#define EDIM 1024
#define DDIM 256
#define PDIM 256

typedef __attribute__((ext_vector_type(8))) short bf16x8;   // 8 bf16 = 4 VGPRs
typedef __attribute__((ext_vector_type(4))) float f32x4;

__device__ __forceinline__ short f2bf(float x) {
    unsigned u = __float_as_uint(x);
    unsigned r = (u + 0x7FFFu + ((u >> 16) & 1u)) >> 16;   // RNE
    return (short)r;
}

// ---------------------------------------------------------------------------
// prep: wT[n][k] = bf16(w[k][n])  (B-operand-friendly layout), and zero the
// row/col sum accumulators + d_out (replaces two hipMemsetAsync dispatches).
// grid 256 x 256 threads.
// ---------------------------------------------------------------------------
__global__ __launch_bounds__(256) void prep_kernel(
    const float* __restrict__ w, ushort* __restrict__ wT,
    float* __restrict__ sums /* row_sums||col_sums, 16384 */,
    float* __restrict__ out, int out_size)
{
    int n = blockIdx.x, k = threadIdx.x;
    wT[(size_t)n * PDIM + k] = (ushort)f2bf(w[(size_t)k * PDIM + n]);
    int g = n * 256 + k;
    if (g < BDIM * UDIM + BDIM * EDIM) sums[g] = 0.f;
    if (g < out_size) out[g] = 0.f;
}

// ---------------------------------------------------------------------------
// proj: u_p/e_p = bf16(enc @ w + bias), MFMA 16x16x32 bf16.
// 16384 rows (u then e) x 256 cols. Block = 64x64 tile, 4 waves, each wave a
// 16-row strip x 64 cols (4 n-tiles). A-frags: fp32 global load + cvt.
// B-frags: direct 16B loads from wT (L1/L2 resident, 128 KB).
// ---------------------------------------------------------------------------
__global__ __launch_bounds__(256) void proj_kernel(
    const float* __restrict__ u_enc, const float* __restrict__ e_enc,
    const ushort* __restrict__ wT, const float* __restrict__ bias,
    ushort* __restrict__ u_p, ushort* __restrict__ e_p)
{
    int row0 = blockIdx.x * 64;
    int col0 = blockIdx.y * 64;
    const float* A; ushort* C;
    if (row0 < BDIM * UDIM) { A = u_enc; C = u_p; }
    else                    { A = e_enc; C = e_p; row0 -= BDIM * UDIM; }

    int tid  = threadIdx.x;
    int wave = tid >> 6, lane = tid & 63;
    int m = lane & 15, quad = lane >> 4;

    const float* aptr = A + (size_t)(row0 + wave * 16 + m) * DDIM + quad * 8;

    f32x4 acc[4] = {};

    #pragma unroll
    for (int k0 = 0; k0 < DDIM; k0 += 32) {
        float4 a0 = *(const float4*)(aptr + k0);
        float4 a1 = *(const float4*)(aptr + k0 + 4);
        bf16x8 af;
        af[0] = f2bf(a0.x); af[1] = f2bf(a0.y); af[2] = f2bf(a0.z); af[3] = f2bf(a0.w);
        af[4] = f2bf(a1.x); af[5] = f2bf(a1.y); af[6] = f2bf(a1.z); af[7] = f2bf(a1.w);
        #pragma unroll
        for (int nt = 0; nt < 4; ++nt) {
            bf16x8 bfr = *(const bf16x8*)(wT + (size_t)(col0 + nt * 16 + m) * DDIM + k0 + quad * 8);
            acc[nt] = __builtin_amdgcn_mfma_f32_16x16x32_bf16(af, bfr, acc[nt], 0, 0, 0);
        }
    }

    // C/D layout: col = lane&15, row = quad*4 + reg.
    #pragma unroll
    for (int nt = 0; nt < 4; ++nt) {
        int col = col0 + nt * 16 + m;
        float bv = bias[col];
        #pragma unroll
        for (int r = 0; r < 4; ++r) {
            int row = row0 + wave * 16 + quad * 4 + r;
            C[(size_t)row * PDIM + col] = (ushort)f2bf(acc[nt][r] + bv);
        }
    }
}

// ---------------------------------------------------------------------------
// fused: op = u_p . e_p (MFMA), gate, row/col reduction. mask never hits HBM.
// Block = 64x64 (u,e) tile; wave = 16-row strip. Frags loaded directly from
// bf16 u_p/e_p in global (per-batch slices are L2-resident).
// ---------------------------------------------------------------------------
__global__ __launch_bounds__(256) void fused_kernel(
    const ushort* __restrict__ u_p, const ushort* __restrict__ e_p,
    const float* __restrict__ pair_enc, const float* __restrict__ ue_mask,
    const float* __restrict__ bpp_w_p, const float* __restrict__ bpp_b_p,
    float* __restrict__ row_sums, float* __restrict__ col_sums)
{
    __shared__ float colred[4][64];

    int b  = blockIdx.y;
    int iu = blockIdx.x >> 4, ie = blockIdx.x & 15;
    int u0 = iu * 64, e0 = ie * 64;

    int tid  = threadIdx.x;
    int wave = tid >> 6, lane = tid & 63;
    int m = lane & 15, quad = lane >> 4;

    const ushort* Au = u_p + (size_t)b * UDIM * PDIM + (size_t)(u0 + wave * 16 + m) * PDIM + quad * 8;
    const ushort* Be = e_p + (size_t)b * EDIM * PDIM + (size_t)(e0 + m) * PDIM + quad * 8;

    f32x4 acc[4] = {};

    #pragma unroll
    for (int k0 = 0; k0 < PDIM; k0 += 32) {
        bf16x8 af = *(const bf16x8*)(Au + k0);
        #pragma unroll
        for (int nt = 0; nt < 4; ++nt) {
            bf16x8 bfr = *(const bf16x8*)(Be + (size_t)nt * 16 * PDIM + k0);
            acc[nt] = __builtin_amdgcn_mfma_f32_16x16x32_bf16(af, bfr, acc[nt], 0, 0, 0);
        }
    }

    // Epilogue: gate + partial sums. C layout: row = quad*4+reg, col = lane&15 (+16*nt).
    float bw = bpp_w_p[0], bb = bpp_b_p[0];
    const float* pm = pair_enc + (size_t)b * UDIM * EDIM;
    const float* mm = ue_mask  + (size_t)b * UDIM * EDIM;

    float rsum[4] = {0.f, 0.f, 0.f, 0.f};
    float csum[4] = {0.f, 0.f, 0.f, 0.f};
    #pragma unroll
    for (int r = 0; r < 4; ++r) {
        int row = u0 + wave * 16 + quad * 4 + r;
        #pragma unroll
        for (int nt = 0; nt < 4; ++nt) {
            int col = e0 + nt * 16 + m;
            size_t idx = (size_t)row * EDIM + col;
            float mv = mm[idx], pv = pm[idx];
            float arg = bw * pv + bb + mv * acc[nt][r];
            float s = mv / (1.f + __expf(-arg));
            rsum[r]  += s;
            csum[nt] += s;
        }
    }

    // Row sums: reduce across the 16 lanes of each quad (cols). Row is unique
    // to (wave, quad, r) -> direct atomicAdd from the quad leader.
    #pragma unroll
    for (int r = 0; r < 4; ++r) {
        float v = rsum[r];
        v += __shfl_xor(v, 1); v += __shfl_xor(v, 2);
        v += __shfl_xor(v, 4); v += __shfl_xor(v, 8);
        if (m == 0)
            atomicAdd(&row_sums[(size_t)b * UDIM + u0 + wave * 16 + quad * 4 + r], v);
    }

    // Col sums: reduce across quads (rows within strip), then across waves via LDS.
    #pragma unroll
    for (int nt = 0; nt < 4; ++nt) {
        float v = csum[nt];
        v += __shfl_xor(v, 16); v += __shfl_xor(v, 32);
        if (quad == 0) colred[wave][nt * 16 + m] = v;
    }
    __syncthreads();

    if (tid < 64) {
        float v = colred[0][tid] + colred[1][tid] + colred[2][tid] + colred[3][tid];
        atomicAdd(&col_sums[(size_t)b * EDIM + e0 + tid], v);
    }
}

// ---------------------------------------------------------------------------
// finish: out[b,0:256] = row_sums[b,:] @ u_enc[b]; out[b,256:512] = col_sums @ e_enc.
// fp32 throughout (accuracy). grid (B,2,16), atomicAdd into zeroed out.
// ---------------------------------------------------------------------------
__global__ __launch_bounds__(256) void finish_kernel(
    const float* __restrict__ u_enc, const float* __restrict__ e_enc,
    const float* __restrict__ row_sums, const float* __restrict__ col_sums,
    float* __restrict__ out)
{
    int b = blockIdx.x;
    int half = blockIdx.y;
    int chunk = blockIdx.z;
    int d = threadIdx.x;

    const float* enc = half ? e_enc : u_enc;
    const float* s   = half ? col_sums : row_sums;

    int base = chunk * 64;
    float acc = 0.f;
    #pragma unroll 4
    for (int u = 0; u < 64; ++u) {
        float sv = s[(size_t)b * UDIM + base + u];
        acc += sv * enc[(size_t)(b * UDIM + base + u) * DDIM + d];
    }
    atomicAdd(&out[(size_t)b * 2 * DDIM + half * DDIM + d], acc);
}

// ---------------------------------------------------------------------------
extern "C" void kernel_launch(void* const* d_in, const int* in_sizes, int n_in,
                              void* d_out, int out_size, void* d_ws, size_t ws_size,
                              hipStream_t stream)
{
    const float* u_enc    = (const float*)d_in[0];
    const float* e_enc    = (const float*)d_in[1];
    const float* pair_enc = (const float*)d_in[2];
    const float* ue_mask  = (const float*)d_in[3];
    const float* w_kernel = (const float*)d_in[4];
    const float* w_bias   = (const float*)d_in[5];
    const float* bpp_w    = (const float*)d_in[6];
    const float* bpp_b    = (const float*)d_in[7];
    float* out = (float*)d_out;

    // ws layout: u_p bf16 (4MB) | e_p bf16 (4MB) | wT bf16 (128KB) | sums fp32 (64KB)
    ushort* u_p = (ushort*)d_ws;
    ushort* e_p = u_p + (size_t)BDIM * UDIM * PDIM;
    ushort* wT  = e_p + (size_t)BDIM * EDIM * PDIM;
    float* row_sums = (float*)(wT + (size_t)DDIM * PDIM);
    float* col_sums = row_sums + BDIM * UDIM;

    prep_kernel<<<dim3(256), 256, 0, stream>>>(w_kernel, wT, row_sums, out, out_size);

    proj_kernel<<<dim3(256, 4), 256, 0, stream>>>(u_enc, e_enc, wT, w_bias, u_p, e_p);

    fused_kernel<<<dim3(256, BDIM), 256, 0, stream>>>(u_p, e_p, pair_enc, ue_mask,
                                                      bpp_w, bpp_b, row_sums, col_sums);

    finish_kernel<<<dim3(BDIM, 2, 16), 256, 0, stream>>>(u_enc, e_enc, row_sums, col_sums, out);
}